// Round 13
// baseline (424.045 us; speedup 1.0000x reference)
//
#include <hip/hip_runtime.h>
#include <hip/hip_bf16.h>
#include <math.h>

#define N_NODES 100000
#define N_EDGES 1600000
#define N_FEAT 64
#define HID 64
#define HL 256
#define N_GRAPHS 512

#define BUCKET_BITS 7
#define BUCKET_SIZE 128
#define NB ((N_NODES + BUCKET_SIZE - 1) / BUCKET_SIZE)   // 782
#define CAP 3584                   // per-bucket capacity incl. per-node 8-pad
#define EDGES_PER_BLOCK 16384
#define SCAT_BLOCKS ((N_EDGES + EDGES_PER_BLOCK - 1) / EDGES_PER_BLOCK)  // 98
#define F2B_BLOCKS (N_NODES * 16 / 256)                                  // 6250
#define WPREP_BLOCKS 128
#define ZOFF ((unsigned int)N_NODES * 128u)   // byte offset of the zero row

typedef short vbf8 __attribute__((ext_vector_type(8)));
typedef float vf4 __attribute__((ext_vector_type(4)));
typedef float vf2 __attribute__((ext_vector_type(2)));

// bf16 helpers (manual RNE; values are finite)
__device__ __forceinline__ unsigned short f2b(float f) {
    unsigned int u = __float_as_uint(f);
    return (unsigned short)((u + 0x7FFFu + ((u >> 16) & 1u)) >> 16);
}
__device__ __forceinline__ float b2f(unsigned short u) {
    return __uint_as_float(((unsigned int)u) << 16);
}
// packed fp32x2 -> bf16x2 (v_cvt_pk_bf16_f32, RNE — identical result to f2b)
__device__ __forceinline__ unsigned pk2(float lo, float hi) {
    float2 f; f.x = lo; f.y = hi;
    __hip_bfloat162 h = __float22bfloat162_rn(f);
    unsigned r;
    __builtin_memcpy(&r, &h, 4);
    return r;
}
// bf16 pair -> float2 {lo, hi} (shift + and; pairs with v_pk_add_f32)
__device__ __forceinline__ vf2 bpair(unsigned int d) {
    vf2 r;
    r.x = __uint_as_float(d << 16);
    r.y = __uint_as_float(d & 0xFFFF0000u);
    return r;
}

// ---------------- mega prep: bucket-scatter + f2b + wprep in one launch ----

__global__ __launch_bounds__(256) void k_mega(
        const int* __restrict__ src, const int* __restrict__ dst,
        int* __restrict__ bcnt, unsigned int* __restrict__ ebuf,
        const float4* __restrict__ x, uint2* __restrict__ xb,
        const float* __restrict__ wroot0, const float* __restrict__ wrel0,
        const float* __restrict__ wroot1, const float* __restrict__ wrel1,
        const float* __restrict__ wroot2, const float* __restrict__ wrel2,
        const float* __restrict__ wroot3, const float* __restrict__ wrel3,
        unsigned short* __restrict__ wt) {
    __shared__ int lh[NB];
    __shared__ int lbase[NB];
    int bid = blockIdx.x;
    int t = threadIdx.x;

    if (bid < SCAT_BLOCKS) {
        // ---- bucket scatter: packed record (src<<7)|(dst&127), fixed CAP ----
        for (int i = t; i < NB; i += 256) lh[i] = 0;
        __syncthreads();
        int i0 = bid * EDGES_PER_BLOCK;
        int i1 = min(N_EDGES, i0 + EDGES_PER_BLOCK);
        for (int i = i0 + t; i < i1; i += 256)
            atomicAdd(&lh[dst[i] >> BUCKET_BITS], 1);
        __syncthreads();
        for (int i = t; i < NB; i += 256) {
            int c = lh[i];
            lbase[i] = c ? atomicAdd(&bcnt[i], c) : 0;
            lh[i] = 0;  // reuse as local cursor
        }
        __syncthreads();
        for (int i = i0 + t; i < i1; i += 256) {
            int s = src[i], d = dst[i];
            int b = d >> BUCKET_BITS;
            int p = b * CAP + lbase[b] + atomicAdd(&lh[b], 1);
            ebuf[p] = ((unsigned int)s << 7) | (unsigned int)(d & 127);
        }
    } else if (bid < SCAT_BLOCKS + F2B_BLOCKS) {
        // ---- fp32 -> bf16 convert (packed cvt) ----
        int i = (bid - SCAT_BLOCKS) * 256 + t;
        if (i < N_NODES * 16) {
            float4 v = x[i];
            uint2 o;
            o.x = pk2(v.x, v.y);
            o.y = pk2(v.z, v.w);
            xb[i] = o;
        }
    } else {
        // ---- weight prep: Wt[layer][n][k], k = [wroot|wrel] ----
        int gi = (bid - SCAT_BLOCKS - F2B_BLOCKS) * 256 + t;
        if (gi < 4 * 64 * 128) {
            int layer = gi >> 13;
            int i = gi & 8191;
            int nn = i >> 7, k = i & 127;
            const float* wr = (layer == 0) ? wroot0 : (layer == 1) ? wroot1
                             : (layer == 2) ? wroot2 : wroot3;
            const float* wl = (layer == 0) ? wrel0 : (layer == 1) ? wrel1
                             : (layer == 2) ? wrel2 : wrel3;
            float v = (k < 64) ? wr[k * 64 + nn] : wl[(k - 64) * 64 + nn];
            wt[gi] = f2b(v);
        }
    }
}

// ---------------- per-bucket: node hist -> padded scan -> re -> soff -------
// Per-node edge lists padded to a multiple of 8 with ZOFF entries (zero-row
// loads), so agg needs NO tail bounds check. Block 0 zeroes the two h-buffer
// zero rows.

__global__ __launch_bounds__(256) void k_fscatter2(const unsigned int* __restrict__ ebuf,
        const int* __restrict__ bcnt, int2* __restrict__ re,
        unsigned int* __restrict__ soff, unsigned short* __restrict__ hbA,
        unsigned short* __restrict__ hbB, int n) {
    __shared__ int lcnt[BUCKET_SIZE];
    __shared__ int sc[BUCKET_SIZE];
    __shared__ int cur[BUCKET_SIZE];
    int b = blockIdx.x;
    int rbase = b * CAP;
    int n0 = b * BUCKET_SIZE;
    int t = threadIdx.x;
    int cb = bcnt[b];
    if (b == 0 && t < 16) {
        // zero the pad rows (128 B each) of both h buffers
        uint4 z = make_uint4(0u, 0u, 0u, 0u);
        unsigned short* hp = (t < 8) ? hbA : hbB;
        ((uint4*)(hp + (size_t)N_NODES * 64))[t & 7] = z;
    }
    if (t < BUCKET_SIZE) lcnt[t] = 0;
    __syncthreads();
    for (int r = t; r < cb; r += 256) {
        unsigned int rec = ebuf[rbase + r];
        atomicAdd(&lcnt[rec & 127u], 1);
    }
    __syncthreads();
    int v = 0, pcnt = 0;
    if (t < BUCKET_SIZE) {
        v = lcnt[t];
        pcnt = (v + 7) & ~7;     // pad to multiple of 8
        sc[t] = pcnt;
    }
    __syncthreads();
    for (int off = 1; off < BUCKET_SIZE; off <<= 1) {
        int x = 0;
        if (t < BUCKET_SIZE) {
            x = sc[t];
            if (t >= off) x += sc[t - off];
        }
        __syncthreads();
        if (t < BUCKET_SIZE) sc[t] = x;
        __syncthreads();
    }
    int start = 0;
    if (t < BUCKET_SIZE) {
        start = rbase + sc[t] - pcnt;   // exclusive scan of padded counts
        if (n0 + t < n) re[n0 + t] = make_int2(start, start + v);
        cur[t] = start;
        // fill this node's pad slots with the zero-row offset
        for (int z = start + v; z < start + pcnt; z++) soff[z] = ZOFF;
    }
    __syncthreads();
    for (int r = t; r < cb; r += 256) {
        unsigned int rec = ebuf[rbase + r];
        int p = atomicAdd(&cur[rec & 127u], 1);
        soff[p] = rec & ~127u;   // src * 128 byte offset
    }
}

// ---------------- aggregation: aggb[i] = sum_{j->i} h[j] (bf16 in/out) -----
// one wave per node; 8 edges per VMEM instruction: lane = q*8+sl,
// q = edge slot (0..7), sl = 16B feature slice (0..7, uint4 load).
// Edge lists 8-padded with zero-row offsets -> NO tail bounds logic.

__global__ __launch_bounds__(256) void k_agg(
    const unsigned short* __restrict__ hb, unsigned short* __restrict__ aggb,
    const int2* __restrict__ re, const unsigned int* __restrict__ soff, int n) {
    int lane = threadIdx.x & 63;
    int i = (blockIdx.x * 256 + threadIdx.x) >> 6;
    if (i >= n) return;
    int q = lane >> 3;
    int sl = lane & 7;
    int2 bounds = re[i];
    int e0 = bounds.x, e1 = bounds.y;
    int iters = (e1 - e0 + 7) >> 3;
    const char* base = (const char*)hb + sl * 16;

    vf2 A[4], B[4];
#pragma unroll
    for (int f = 0; f < 4; f++) { A[f] = (vf2){0.f, 0.f}; B[f] = (vf2){0.f, 0.f}; }

    int eq = e0 + q;
    int it = 0;
    for (; it + 2 <= iters; it += 2) {
        int ea = eq + it * 8, eb = ea + 8;
        unsigned oa = __builtin_nontemporal_load(soff + ea);
        unsigned ob = __builtin_nontemporal_load(soff + eb);
        uint4 da = *(const uint4*)(base + oa);
        uint4 db = *(const uint4*)(base + ob);
        A[0] += bpair(da.x); A[1] += bpair(da.y);
        A[2] += bpair(da.z); A[3] += bpair(da.w);
        B[0] += bpair(db.x); B[1] += bpair(db.y);
        B[2] += bpair(db.z); B[3] += bpair(db.w);
    }
    if (it < iters) {
        int ea = eq + it * 8;
        unsigned oa = __builtin_nontemporal_load(soff + ea);
        uint4 da = *(const uint4*)(base + oa);
        A[0] += bpair(da.x); A[1] += bpair(da.y);
        A[2] += bpair(da.z); A[3] += bpair(da.w);
    }

    float f[8];
#pragma unroll
    for (int k = 0; k < 4; k++) {
        vf2 s2 = A[k] + B[k];
        float slo = s2.x, shi = s2.y;
        slo += __shfl_xor(slo, 8);
        slo += __shfl_xor(slo, 16);
        slo += __shfl_xor(slo, 32);
        shi += __shfl_xor(shi, 8);
        shi += __shfl_xor(shi, 16);
        shi += __shfl_xor(shi, 32);
        f[2 * k] = slo;
        f[2 * k + 1] = shi;
    }
    if (q == 0) {
        uint4 o;
        o.x = pk2(f[0], f[1]);
        o.y = pk2(f[2], f[3]);
        o.z = pk2(f[4], f[5]);
        o.w = pk2(f[6], f[7]);
        *(uint4*)((char*)aggb + (size_t)i * 128 + sl * 16) = o;
    }
}

// ---------------- MFMA gemm: hbout = [relu]([hb|aggb] @ Wt^T + brel) -------

template <int RELU>
__global__ __launch_bounds__(256) void k_gemm(
    const unsigned short* __restrict__ hb, const unsigned short* __restrict__ aggb,
    const unsigned short* __restrict__ wt, const float* __restrict__ brel,
    unsigned short* __restrict__ hbout, int n) {
    __shared__ float sc[4][16 * 68];

    int tid = threadIdx.x;
    int w = tid >> 6, l = tid & 63;
    int lm = l & 15, q = l >> 4;
    int r0 = blockIdx.x * 64 + w * 16;

    int arow = r0 + lm;
    if (arow >= n) arow = n - 1;
    const unsigned short* ah = hb + (size_t)arow * 64 + q * 8;
    const unsigned short* aa = aggb + (size_t)arow * 64 + q * 8;
    vbf8 afr[4];
    afr[0] = *(const vbf8*)(ah);
    afr[1] = *(const vbf8*)(ah + 32);
    afr[2] = *(const vbf8*)(aa);
    afr[3] = *(const vbf8*)(aa + 32);

    vf4 acc[4];
#pragma unroll
    for (int t = 0; t < 4; t++) acc[t] = (vf4){0.f, 0.f, 0.f, 0.f};

#pragma unroll
    for (int t = 0; t < 4; t++) {
        const unsigned short* wrow = wt + (size_t)(t * 16 + lm) * 128 + q * 8;
#pragma unroll
        for (int s = 0; s < 4; s++) {
            vbf8 bfr = *(const vbf8*)(wrow + s * 32);
            acc[t] = __builtin_amdgcn_mfma_f32_16x16x32_bf16(afr[s], bfr, acc[t], 0, 0, 0);
        }
    }

    float* sw_ = sc[w];
#pragma unroll
    for (int t = 0; t < 4; t++) {
        float b = brel[t * 16 + lm];
#pragma unroll
        for (int i = 0; i < 4; i++) {
            float v = acc[t][i] + b;
            if (RELU) v = fmaxf(v, 0.f);
            sw_[(q * 4 + i) * 68 + t * 16 + lm] = v;
        }
    }
    int rr = l >> 2, cs = l & 3;
    int node = r0 + rr;
    if (node < n) {
        const float* rp = sw_ + rr * 68 + cs * 16;
        float4 v0 = *(const float4*)(rp);
        float4 v1 = *(const float4*)(rp + 4);
        float4 v2 = *(const float4*)(rp + 8);
        float4 v3 = *(const float4*)(rp + 12);
        uint4 o0, o1;
        o0.x = pk2(v0.x, v0.y);
        o0.y = pk2(v0.z, v0.w);
        o0.z = pk2(v1.x, v1.y);
        o0.w = pk2(v1.z, v1.w);
        o1.x = pk2(v2.x, v2.y);
        o1.y = pk2(v2.z, v2.w);
        o1.z = pk2(v3.x, v3.y);
        o1.w = pk2(v3.z, v3.w);
        uint4* op = (uint4*)(hbout + (size_t)node * 64 + cs * 16);
        op[0] = o0;
        op[1] = o1;
    }
}

// ---------------- fused pool + MLP head (one block per graph) --------------

__global__ __launch_bounds__(256) void k_poolmlp(
    const unsigned short* __restrict__ hb, const int* __restrict__ batch,
    const float* __restrict__ T, const float* __restrict__ w1,
    const float* __restrict__ b1, const float* __restrict__ w2,
    const float* __restrict__ b2, const float* __restrict__ w3,
    const float* __restrict__ b3, float* __restrict__ out, int n) {
    __shared__ float psum[4][64];
    __shared__ float pmax[4][64];
    __shared__ float sin_[200];
    __shared__ float so1[256];
    __shared__ float red[256];
    int g = blockIdx.x, t = threadIdx.x;
    int l = t & 63, c = t >> 6;

    // bounds via binary search (batch sorted)
    int lo = 0, hi = n;
    while (lo < hi) { int m = (lo + hi) >> 1; if (batch[m] < g) lo = m + 1; else hi = m; }
    int s0 = lo;
    int lo2 = s0, hi2 = n;
    while (lo2 < hi2) { int m = (lo2 + hi2) >> 1; if (batch[m] < g + 1) lo2 = m + 1; else hi2 = m; }
    int s1 = lo2;

    // pooling: unroll x4 (independent loads in flight)
    float sa0 = 0.f, sa1 = 0.f, sa2 = 0.f, sa3 = 0.f;
    float ma0 = -INFINITY, ma1 = -INFINITY, ma2 = -INFINITY, ma3 = -INFINITY;
    int nn = s0 + c;
    for (; nn + 12 < s1; nn += 16) {
        float v0 = b2f(hb[(size_t)nn * 64 + l]);
        float v1 = b2f(hb[(size_t)(nn + 4) * 64 + l]);
        float v2 = b2f(hb[(size_t)(nn + 8) * 64 + l]);
        float v3 = b2f(hb[(size_t)(nn + 12) * 64 + l]);
        sa0 += v0; sa1 += v1; sa2 += v2; sa3 += v3;
        ma0 = fmaxf(ma0, v0); ma1 = fmaxf(ma1, v1);
        ma2 = fmaxf(ma2, v2); ma3 = fmaxf(ma3, v3);
    }
    for (; nn < s1; nn += 4) {
        float v = b2f(hb[(size_t)nn * 64 + l]);
        sa0 += v;
        ma0 = fmaxf(ma0, v);
    }
    psum[c][l] = (sa0 + sa1) + (sa2 + sa3);
    pmax[c][l] = fmaxf(fmaxf(ma0, ma1), fmaxf(ma2, ma3));
    __syncthreads();
    if (t < 64) {
        float s = (psum[0][t] + psum[1][t]) + (psum[2][t] + psum[3][t]);
        float mx = fmaxf(fmaxf(pmax[0][t], pmax[1][t]), fmaxf(pmax[2][t], pmax[3][t]));
        int cnt = s1 - s0;
        float mean = s / fmaxf((float)cnt, 1.f);
        if (cnt == 0) mx = 0.f;
        sin_[t] = mx;
        sin_[64 + t] = mean;
        sin_[128 + t] = s;
        if (t == 0) {
            sin_[192] = T[g];
#pragma unroll
            for (int z = 193; z < 200; z++) sin_[z] = 0.f;  // pad for x8 batch
        }
    }
    __syncthreads();

    // layer 1: 193-K matvec, batched x8 (pad zeros make 200 safe)
    float a = b1[t];
    {
        float wv[8];
        for (int k = 0; k < 192; k += 8) {
#pragma unroll
            for (int u = 0; u < 8; u++) wv[u] = w1[(k + u) * 256 + t];
#pragma unroll
            for (int u = 0; u < 8; u++) a += sin_[k + u] * wv[u];
        }
        a += sin_[192] * w1[192 * 256 + t];
    }
    a = fmaxf(a, 0.f);
    so1[t] = a;
    __syncthreads();

    // layer 2: 256-K matvec, batched x8
    float a2 = b2[t];
    {
        float wv[8];
        for (int k = 0; k < 256; k += 8) {
#pragma unroll
            for (int u = 0; u < 8; u++) wv[u] = w2[(k + u) * 256 + t];
#pragma unroll
            for (int u = 0; u < 8; u++) a2 += so1[k + u] * wv[u];
        }
    }
    a2 = fmaxf(a2, 0.f);
    red[t] = a2 * w3[t];
    __syncthreads();
    for (int s = 128; s > 0; s >>= 1) {
        if (t < s) red[t] += red[t + s];
        __syncthreads();
    }
    if (t == 0) out[g] = red[0] + b3[0];
}

extern "C" void kernel_launch(void* const* d_in, const int* in_sizes, int n_in,
                              void* d_out, int out_size, void* d_ws, size_t ws_size,
                              hipStream_t stream) {
    const int N = N_NODES, E = N_EDGES, G = N_GRAPHS;

    const float* x = (const float*)d_in[0];
    const int* ei = (const int*)d_in[1];
    const int* batch = (const int*)d_in[2];
    const float* T = (const float*)d_in[3];
    const float* wrel[4] = {(const float*)d_in[4], (const float*)d_in[7],
                            (const float*)d_in[10], (const float*)d_in[13]};
    const float* brel[4] = {(const float*)d_in[5], (const float*)d_in[8],
                            (const float*)d_in[11], (const float*)d_in[14]};
    const float* wroot[4] = {(const float*)d_in[6], (const float*)d_in[9],
                             (const float*)d_in[12], (const float*)d_in[15]};
    const float* w1 = (const float*)d_in[16];
    const float* b1 = (const float*)d_in[17];
    const float* w2 = (const float*)d_in[18];
    const float* b2 = (const float*)d_in[19];
    const float* w3 = (const float*)d_in[20];
    const float* b3 = (const float*)d_in[21];
    float* out = (float*)d_out;

    const int* esrc = ei;
    const int* edst = ei + E;

    // workspace layout (~63 MB)
    char* ws = (char*)d_ws;
    size_t off = 0;
    auto alloc = [&](size_t bytes) {
        size_t r = off;
        off = (off + bytes + 255) & ~(size_t)255;
        return r;
    };
    int* bcnt = (int*)(ws + alloc((size_t)NB * 4));
    int2* re = (int2*)(ws + alloc((size_t)N * 8));
    unsigned int* soff = (unsigned int*)(ws + alloc((size_t)NB * CAP * 4));
    unsigned int* ebuf = (unsigned int*)(ws + alloc((size_t)NB * CAP * 4));
    unsigned short* hbA = (unsigned short*)(ws + alloc((size_t)N * 64 * 2 + 128));
    unsigned short* hbB = (unsigned short*)(ws + alloc((size_t)N * 64 * 2 + 128));
    unsigned short* aggb = (unsigned short*)(ws + alloc((size_t)N * 64 * 2));
    unsigned short* wt = (unsigned short*)(ws + alloc((size_t)4 * 64 * 128 * 2));

    // 1. prep: zero bucket counts, then mega (scatter + f2b + wprep)
    hipMemsetAsync(bcnt, 0, (size_t)NB * 4, stream);
    k_mega<<<SCAT_BLOCKS + F2B_BLOCKS + WPREP_BLOCKS, 256, 0, stream>>>(
        esrc, edst, bcnt, ebuf, (const float4*)x, (uint2*)hbA,
        wroot[0], wrel[0], wroot[1], wrel[1],
        wroot[2], wrel[2], wroot[3], wrel[3], wt);
    k_fscatter2<<<NB, 256, 0, stream>>>(ebuf, bcnt, re, soff, hbA, hbB, N);

    // 2. four conv layers (bf16 h ping-pong, MFMA gemm)
    int agg_blocks = (N * 64 + 255) / 256;   // one wave per node
    int gemm_blocks = (N + 63) / 64;         // 64-node tile per block

    k_agg<<<agg_blocks, 256, 0, stream>>>(hbA, aggb, re, soff, N);
    k_gemm<1><<<gemm_blocks, 256, 0, stream>>>(hbA, aggb, wt + 0 * 8192, brel[0], hbB, N);

    k_agg<<<agg_blocks, 256, 0, stream>>>(hbB, aggb, re, soff, N);
    k_gemm<1><<<gemm_blocks, 256, 0, stream>>>(hbB, aggb, wt + 1 * 8192, brel[1], hbA, N);

    k_agg<<<agg_blocks, 256, 0, stream>>>(hbA, aggb, re, soff, N);
    k_gemm<1><<<gemm_blocks, 256, 0, stream>>>(hbA, aggb, wt + 2 * 8192, brel[2], hbB, N);

    k_agg<<<agg_blocks, 256, 0, stream>>>(hbB, aggb, re, soff, N);
    k_gemm<0><<<gemm_blocks, 256, 0, stream>>>(hbB, aggb, wt + 3 * 8192, brel[3], hbA, N);

    // 3. fused pooling + MLP head
    k_poolmlp<<<G, 256, 0, stream>>>(hbA, batch, T, w1, b1, w2, b2, w3, b3, out, N);
}

// Round 14
// 398.786 us; speedup vs baseline: 1.0633x; 1.0633x over previous
//
#include <hip/hip_runtime.h>
#include <hip/hip_bf16.h>
#include <math.h>

#define N_NODES 100000
#define N_EDGES 1600000
#define N_FEAT 64
#define HID 64
#define HL 256
#define N_GRAPHS 512

#define BUCKET_BITS 7
#define BUCKET_SIZE 128
#define NB ((N_NODES + BUCKET_SIZE - 1) / BUCKET_SIZE)   // 782
#define LOFS_W (NB + 1)                                  // 783
#define CAP 3584                   // per-bucket soff capacity incl. 8-pads
#define LREC_CAP 3584              // staged records per bucket (max ~2300)
#define EDGES_PER_BLOCK 4096
#define SCAT_BLOCKS ((N_EDGES + EDGES_PER_BLOCK - 1) / EDGES_PER_BLOCK)  // 391
#define F2B_BLOCKS (N_NODES * 16 / 256)                                  // 6250
#define WPREP_BLOCKS 128
#define ZOFF ((unsigned int)N_NODES * 128u)   // byte offset of the zero row

typedef short vbf8 __attribute__((ext_vector_type(8)));
typedef float vf4 __attribute__((ext_vector_type(4)));
typedef float vf2 __attribute__((ext_vector_type(2)));

// bf16 helpers (manual RNE; values are finite)
__device__ __forceinline__ unsigned short f2b(float f) {
    unsigned int u = __float_as_uint(f);
    return (unsigned short)((u + 0x7FFFu + ((u >> 16) & 1u)) >> 16);
}
__device__ __forceinline__ float b2f(unsigned short u) {
    return __uint_as_float(((unsigned int)u) << 16);
}
// packed fp32x2 -> bf16x2 (v_cvt_pk_bf16_f32, RNE — identical to f2b)
__device__ __forceinline__ unsigned pk2(float lo, float hi) {
    float2 f; f.x = lo; f.y = hi;
    __hip_bfloat162 h = __float22bfloat162_rn(f);
    unsigned r;
    __builtin_memcpy(&r, &h, 4);
    return r;
}
// bf16 pair -> float2 {lo, hi} (shift + and; pairs with v_pk_add_f32)
__device__ __forceinline__ vf2 bpair(unsigned int d) {
    vf2 r;
    r.x = __uint_as_float(d << 16);
    r.y = __uint_as_float(d & 0xFFFF0000u);
    return r;
}

// ---------------- mega prep: LDS bucket-sort + f2b + wprep -----------------
// Scatter branch: block bucket-sorts its 4096 records in LDS, streams out one
// coalesced contiguous run (ebuf write amp = 1), writes its lofs row.
// NO global atomics anywhere.

__global__ __launch_bounds__(256) void k_mega(
        const int* __restrict__ src, const int* __restrict__ dst,
        int* __restrict__ lofs, unsigned int* __restrict__ ebuf,
        const float4* __restrict__ x, uint2* __restrict__ xb,
        const float* __restrict__ wroot0, const float* __restrict__ wrel0,
        const float* __restrict__ wroot1, const float* __restrict__ wrel1,
        const float* __restrict__ wroot2, const float* __restrict__ wrel2,
        const float* __restrict__ wroot3, const float* __restrict__ wrel3,
        unsigned short* __restrict__ wt) {
    __shared__ int lh[NB];
    __shared__ int lsc[256];
    __shared__ unsigned lrec[EDGES_PER_BLOCK];
    int bid = blockIdx.x;
    int t = threadIdx.x;

    if (bid < SCAT_BLOCKS) {
        for (int i = t; i < NB; i += 256) lh[i] = 0;
        __syncthreads();
        int i0 = bid * EDGES_PER_BLOCK;
        int i1 = min(N_EDGES, i0 + EDGES_PER_BLOCK);
        int cnt = i1 - i0;
        for (int i = i0 + t; i < i1; i += 256)
            atomicAdd(&lh[dst[i] >> BUCKET_BITS], 1);
        __syncthreads();
        // exclusive scan of lh[0..NB), 4 entries/thread
        int v[4];
        int s = 0;
        int base4 = t * 4;
#pragma unroll
        for (int j = 0; j < 4; j++) {
            v[j] = (base4 + j < NB) ? lh[base4 + j] : 0;
            s += v[j];
        }
        lsc[t] = s;
        __syncthreads();
        for (int off = 1; off < 256; off <<= 1) {
            int xx = lsc[t];
            int y = (t >= off) ? lsc[t - off] : 0;
            __syncthreads();
            lsc[t] = xx + y;
            __syncthreads();
        }
        int run = lsc[t] - s;   // exclusive prefix
        int* lrow = lofs + (size_t)bid * LOFS_W;
#pragma unroll
        for (int j = 0; j < 4; j++) {
            int b = base4 + j;
            if (b < NB) {
                lrow[b] = run;
                lh[b] = run;   // LDS cursor (all lh reads completed pre-scan)
            }
            run += v[j];
        }
        if (t == 255) lrow[NB] = cnt;
        __syncthreads();
        // scatter into LDS
        for (int i = i0 + t; i < i1; i += 256) {
            int sN = src[i], d = dst[i];
            int b = d >> BUCKET_BITS;
            int p = atomicAdd(&lh[b], 1);
            lrec[p] = ((unsigned)sN << 7) | (unsigned)(d & 127);
        }
        __syncthreads();
        // stream out coalesced
        unsigned* eb = ebuf + (size_t)bid * EDGES_PER_BLOCK;
        for (int j = t; j < cnt; j += 256) eb[j] = lrec[j];
    } else if (bid < SCAT_BLOCKS + F2B_BLOCKS) {
        // ---- fp32 -> bf16 convert (packed cvt) ----
        int i = (bid - SCAT_BLOCKS) * 256 + t;
        if (i < N_NODES * 16) {
            float4 v = x[i];
            uint2 o;
            o.x = pk2(v.x, v.y);
            o.y = pk2(v.z, v.w);
            xb[i] = o;
        }
    } else {
        // ---- weight prep: Wt[layer][n][k], k = [wroot|wrel] ----
        int gi = (bid - SCAT_BLOCKS - F2B_BLOCKS) * 256 + t;
        if (gi < 4 * 64 * 128) {
            int layer = gi >> 13;
            int i = gi & 8191;
            int nn = i >> 7, k = i & 127;
            const float* wr = (layer == 0) ? wroot0 : (layer == 1) ? wroot1
                             : (layer == 2) ? wroot2 : wroot3;
            const float* wl = (layer == 0) ? wrel0 : (layer == 1) ? wrel1
                             : (layer == 2) ? wrel2 : wrel3;
            float v = (k < 64) ? wr[k * 64 + nn] : wl[(k - 64) * 64 + nn];
            wt[gi] = f2b(v);
        }
    }
}

// ---------------- per-bucket: gather runs -> hist -> padded scan -> soff ---
// Phase 0 reconstructs the bucket: scan the 391 per-block run counts
// (lofs[blk][b+1]-lofs[blk][b]) and gather runs into LDS. Then r13 logic:
// per-node 8-padded edge lists with ZOFF pads (no tail check in agg).

__global__ __launch_bounds__(256) void k_fscatter2(
        const unsigned int* __restrict__ ebuf, const int* __restrict__ lofs,
        int2* __restrict__ re, unsigned int* __restrict__ soff,
        unsigned short* __restrict__ hbA, unsigned short* __restrict__ hbB, int n) {
    __shared__ int rcnt[512];
    __shared__ int rbase[512];
    __shared__ int rpre[512];
    __shared__ int tsc[256];
    __shared__ unsigned lrec[LREC_CAP];
    __shared__ int lcnt[BUCKET_SIZE];
    __shared__ int sc[BUCKET_SIZE];
    __shared__ int cur[BUCKET_SIZE];
    int b = blockIdx.x;
    int n0 = b * BUCKET_SIZE;
    int t = threadIdx.x;
    if (b == 0 && t < 16) {
        // zero the pad rows (128 B each) of both h buffers
        uint4 z = make_uint4(0u, 0u, 0u, 0u);
        unsigned short* hp = (t < 8) ? hbA : hbB;
        ((uint4*)(hp + (size_t)N_NODES * 64))[t & 7] = z;
    }
    // load per-block run counts/bases for this bucket
    for (int blk = t; blk < 512; blk += 256) {
        int c = 0, ba = 0;
        if (blk < SCAT_BLOCKS) {
            const int* lr = lofs + (size_t)blk * LOFS_W + b;
            ba = lr[0];
            c = lr[1] - ba;
        }
        rcnt[blk] = c;
        rbase[blk] = ba;
    }
    __syncthreads();
    // scan 512 run counts (2 per thread)
    int c0 = rcnt[2 * t], c1 = rcnt[2 * t + 1];
    tsc[t] = c0 + c1;
    __syncthreads();
    for (int off = 1; off < 256; off <<= 1) {
        int xx = tsc[t];
        int y = (t >= off) ? tsc[t - off] : 0;
        __syncthreads();
        tsc[t] = xx + y;
        __syncthreads();
    }
    int ex = tsc[t] - (c0 + c1);
    rpre[2 * t] = ex;
    rpre[2 * t + 1] = ex + c0;
    __syncthreads();
    int cb = tsc[255];   // total records in this bucket
    // gather runs into LDS
    for (int blk = t; blk < SCAT_BLOCKS; blk += 256) {
        int c = rcnt[blk];
        int dsto = rpre[blk];
        const unsigned* sp = ebuf + (size_t)blk * EDGES_PER_BLOCK + rbase[blk];
        for (int j = 0; j < c; j++) lrec[dsto + j] = sp[j];
    }
    if (t < BUCKET_SIZE) lcnt[t] = 0;
    __syncthreads();
    // per-node histogram
    for (int r = t; r < cb; r += 256)
        atomicAdd(&lcnt[lrec[r] & 127u], 1);
    __syncthreads();
    int v = 0, pcnt = 0;
    if (t < BUCKET_SIZE) {
        v = lcnt[t];
        pcnt = (v + 7) & ~7;     // pad to multiple of 8
        sc[t] = pcnt;
    }
    __syncthreads();
    for (int off = 1; off < BUCKET_SIZE; off <<= 1) {
        int xx = 0;
        if (t < BUCKET_SIZE) {
            xx = sc[t];
            if (t >= off) xx += sc[t - off];
        }
        __syncthreads();
        if (t < BUCKET_SIZE) sc[t] = xx;
        __syncthreads();
    }
    if (t < BUCKET_SIZE) {
        int start = b * CAP + sc[t] - pcnt;   // exclusive scan of padded counts
        if (n0 + t < n) re[n0 + t] = make_int2(start, start + v);
        cur[t] = start;
        for (int z = start + v; z < start + pcnt; z++) soff[z] = ZOFF;
    }
    __syncthreads();
    for (int r = t; r < cb; r += 256) {
        unsigned rec = lrec[r];
        int p = atomicAdd(&cur[rec & 127u], 1);
        soff[p] = rec & ~127u;   // src * 128 byte offset
    }
}

// ---------------- aggregation: aggb[i] = sum_{j->i} h[j] (bf16 in/out) -----
// one wave per node; 8 edges per VMEM instruction: lane = q*8+sl,
// q = edge slot (0..7), sl = 16B feature slice (0..7, uint4 load).
// Edge lists 8-padded with zero-row offsets -> NO tail bounds logic.

__global__ __launch_bounds__(256) void k_agg(
    const unsigned short* __restrict__ hb, unsigned short* __restrict__ aggb,
    const int2* __restrict__ re, const unsigned int* __restrict__ soff, int n) {
    int lane = threadIdx.x & 63;
    int i = (blockIdx.x * 256 + threadIdx.x) >> 6;
    if (i >= n) return;
    int q = lane >> 3;
    int sl = lane & 7;
    int2 bounds = re[i];
    int e0 = bounds.x, e1 = bounds.y;
    int iters = (e1 - e0 + 7) >> 3;
    const char* base = (const char*)hb + sl * 16;

    vf2 A[4], B[4];
#pragma unroll
    for (int f = 0; f < 4; f++) { A[f] = (vf2){0.f, 0.f}; B[f] = (vf2){0.f, 0.f}; }

    int eq = e0 + q;
    int it = 0;
    for (; it + 2 <= iters; it += 2) {
        int ea = eq + it * 8, eb = ea + 8;
        unsigned oa = __builtin_nontemporal_load(soff + ea);
        unsigned ob = __builtin_nontemporal_load(soff + eb);
        uint4 da = *(const uint4*)(base + oa);
        uint4 db = *(const uint4*)(base + ob);
        A[0] += bpair(da.x); A[1] += bpair(da.y);
        A[2] += bpair(da.z); A[3] += bpair(da.w);
        B[0] += bpair(db.x); B[1] += bpair(db.y);
        B[2] += bpair(db.z); B[3] += bpair(db.w);
    }
    if (it < iters) {
        int ea = eq + it * 8;
        unsigned oa = __builtin_nontemporal_load(soff + ea);
        uint4 da = *(const uint4*)(base + oa);
        A[0] += bpair(da.x); A[1] += bpair(da.y);
        A[2] += bpair(da.z); A[3] += bpair(da.w);
    }

    float f[8];
#pragma unroll
    for (int k = 0; k < 4; k++) {
        vf2 s2 = A[k] + B[k];
        float slo = s2.x, shi = s2.y;
        slo += __shfl_xor(slo, 8);
        slo += __shfl_xor(slo, 16);
        slo += __shfl_xor(slo, 32);
        shi += __shfl_xor(shi, 8);
        shi += __shfl_xor(shi, 16);
        shi += __shfl_xor(shi, 32);
        f[2 * k] = slo;
        f[2 * k + 1] = shi;
    }
    if (q == 0) {
        uint4 o;
        o.x = pk2(f[0], f[1]);
        o.y = pk2(f[2], f[3]);
        o.z = pk2(f[4], f[5]);
        o.w = pk2(f[6], f[7]);
        *(uint4*)((char*)aggb + (size_t)i * 128 + sl * 16) = o;
    }
}

// ---------------- MFMA gemm: hbout = [relu]([hb|aggb] @ Wt^T + brel) -------

template <int RELU>
__global__ __launch_bounds__(256) void k_gemm(
    const unsigned short* __restrict__ hb, const unsigned short* __restrict__ aggb,
    const unsigned short* __restrict__ wt, const float* __restrict__ brel,
    unsigned short* __restrict__ hbout, int n) {
    __shared__ float sc[4][16 * 68];

    int tid = threadIdx.x;
    int w = tid >> 6, l = tid & 63;
    int lm = l & 15, q = l >> 4;
    int r0 = blockIdx.x * 64 + w * 16;

    int arow = r0 + lm;
    if (arow >= n) arow = n - 1;
    const unsigned short* ah = hb + (size_t)arow * 64 + q * 8;
    const unsigned short* aa = aggb + (size_t)arow * 64 + q * 8;
    vbf8 afr[4];
    afr[0] = *(const vbf8*)(ah);
    afr[1] = *(const vbf8*)(ah + 32);
    afr[2] = *(const vbf8*)(aa);
    afr[3] = *(const vbf8*)(aa + 32);

    vf4 acc[4];
#pragma unroll
    for (int t = 0; t < 4; t++) acc[t] = (vf4){0.f, 0.f, 0.f, 0.f};

#pragma unroll
    for (int t = 0; t < 4; t++) {
        const unsigned short* wrow = wt + (size_t)(t * 16 + lm) * 128 + q * 8;
#pragma unroll
        for (int s = 0; s < 4; s++) {
            vbf8 bfr = *(const vbf8*)(wrow + s * 32);
            acc[t] = __builtin_amdgcn_mfma_f32_16x16x32_bf16(afr[s], bfr, acc[t], 0, 0, 0);
        }
    }

    float* sw_ = sc[w];
#pragma unroll
    for (int t = 0; t < 4; t++) {
        float b = brel[t * 16 + lm];
#pragma unroll
        for (int i = 0; i < 4; i++) {
            float v = acc[t][i] + b;
            if (RELU) v = fmaxf(v, 0.f);
            sw_[(q * 4 + i) * 68 + t * 16 + lm] = v;
        }
    }
    int rr = l >> 2, cs = l & 3;
    int node = r0 + rr;
    if (node < n) {
        const float* rp = sw_ + rr * 68 + cs * 16;
        float4 v0 = *(const float4*)(rp);
        float4 v1 = *(const float4*)(rp + 4);
        float4 v2 = *(const float4*)(rp + 8);
        float4 v3 = *(const float4*)(rp + 12);
        uint4 o0, o1;
        o0.x = pk2(v0.x, v0.y);
        o0.y = pk2(v0.z, v0.w);
        o0.z = pk2(v1.x, v1.y);
        o0.w = pk2(v1.z, v1.w);
        o1.x = pk2(v2.x, v2.y);
        o1.y = pk2(v2.z, v2.w);
        o1.z = pk2(v3.x, v3.y);
        o1.w = pk2(v3.z, v3.w);
        uint4* op = (uint4*)(hbout + (size_t)node * 64 + cs * 16);
        op[0] = o0;
        op[1] = o1;
    }
}

// ---------------- fused pool + MLP head (one block per graph) --------------

__global__ __launch_bounds__(256) void k_poolmlp(
    const unsigned short* __restrict__ hb, const int* __restrict__ batch,
    const float* __restrict__ T, const float* __restrict__ w1,
    const float* __restrict__ b1, const float* __restrict__ w2,
    const float* __restrict__ b2, const float* __restrict__ w3,
    const float* __restrict__ b3, float* __restrict__ out, int n) {
    __shared__ float psum[4][64];
    __shared__ float pmax[4][64];
    __shared__ float sin_[200];
    __shared__ float so1[256];
    __shared__ float red[256];
    int g = blockIdx.x, t = threadIdx.x;
    int l = t & 63, c = t >> 6;

    // bounds via binary search (batch sorted)
    int lo = 0, hi = n;
    while (lo < hi) { int m = (lo + hi) >> 1; if (batch[m] < g) lo = m + 1; else hi = m; }
    int s0 = lo;
    int lo2 = s0, hi2 = n;
    while (lo2 < hi2) { int m = (lo2 + hi2) >> 1; if (batch[m] < g + 1) lo2 = m + 1; else hi2 = m; }
    int s1 = lo2;

    // pooling: unroll x4 (independent loads in flight)
    float sa0 = 0.f, sa1 = 0.f, sa2 = 0.f, sa3 = 0.f;
    float ma0 = -INFINITY, ma1 = -INFINITY, ma2 = -INFINITY, ma3 = -INFINITY;
    int nn = s0 + c;
    for (; nn + 12 < s1; nn += 16) {
        float v0 = b2f(hb[(size_t)nn * 64 + l]);
        float v1 = b2f(hb[(size_t)(nn + 4) * 64 + l]);
        float v2 = b2f(hb[(size_t)(nn + 8) * 64 + l]);
        float v3 = b2f(hb[(size_t)(nn + 12) * 64 + l]);
        sa0 += v0; sa1 += v1; sa2 += v2; sa3 += v3;
        ma0 = fmaxf(ma0, v0); ma1 = fmaxf(ma1, v1);
        ma2 = fmaxf(ma2, v2); ma3 = fmaxf(ma3, v3);
    }
    for (; nn < s1; nn += 4) {
        float v = b2f(hb[(size_t)nn * 64 + l]);
        sa0 += v;
        ma0 = fmaxf(ma0, v);
    }
    psum[c][l] = (sa0 + sa1) + (sa2 + sa3);
    pmax[c][l] = fmaxf(fmaxf(ma0, ma1), fmaxf(ma2, ma3));
    __syncthreads();
    if (t < 64) {
        float s = (psum[0][t] + psum[1][t]) + (psum[2][t] + psum[3][t]);
        float mx = fmaxf(fmaxf(pmax[0][t], pmax[1][t]), fmaxf(pmax[2][t], pmax[3][t]));
        int cnt = s1 - s0;
        float mean = s / fmaxf((float)cnt, 1.f);
        if (cnt == 0) mx = 0.f;
        sin_[t] = mx;
        sin_[64 + t] = mean;
        sin_[128 + t] = s;
        if (t == 0) {
            sin_[192] = T[g];
#pragma unroll
            for (int z = 193; z < 200; z++) sin_[z] = 0.f;  // pad for x8 batch
        }
    }
    __syncthreads();

    // layer 1: 193-K matvec, batched x8 (pad zeros make 200 safe)
    float a = b1[t];
    {
        float wv[8];
        for (int k = 0; k < 192; k += 8) {
#pragma unroll
            for (int u = 0; u < 8; u++) wv[u] = w1[(k + u) * 256 + t];
#pragma unroll
            for (int u = 0; u < 8; u++) a += sin_[k + u] * wv[u];
        }
        a += sin_[192] * w1[192 * 256 + t];
    }
    a = fmaxf(a, 0.f);
    so1[t] = a;
    __syncthreads();

    // layer 2: 256-K matvec, batched x8
    float a2 = b2[t];
    {
        float wv[8];
        for (int k = 0; k < 256; k += 8) {
#pragma unroll
            for (int u = 0; u < 8; u++) wv[u] = w2[(k + u) * 256 + t];
#pragma unroll
            for (int u = 0; u < 8; u++) a2 += so1[k + u] * wv[u];
        }
    }
    a2 = fmaxf(a2, 0.f);
    red[t] = a2 * w3[t];
    __syncthreads();
    for (int s = 128; s > 0; s >>= 1) {
        if (t < s) red[t] += red[t + s];
        __syncthreads();
    }
    if (t == 0) out[g] = red[0] + b3[0];
}

extern "C" void kernel_launch(void* const* d_in, const int* in_sizes, int n_in,
                              void* d_out, int out_size, void* d_ws, size_t ws_size,
                              hipStream_t stream) {
    const int N = N_NODES, E = N_EDGES, G = N_GRAPHS;

    const float* x = (const float*)d_in[0];
    const int* ei = (const int*)d_in[1];
    const int* batch = (const int*)d_in[2];
    const float* T = (const float*)d_in[3];
    const float* wrel[4] = {(const float*)d_in[4], (const float*)d_in[7],
                            (const float*)d_in[10], (const float*)d_in[13]};
    const float* brel[4] = {(const float*)d_in[5], (const float*)d_in[8],
                            (const float*)d_in[11], (const float*)d_in[14]};
    const float* wroot[4] = {(const float*)d_in[6], (const float*)d_in[9],
                             (const float*)d_in[12], (const float*)d_in[15]};
    const float* w1 = (const float*)d_in[16];
    const float* b1 = (const float*)d_in[17];
    const float* w2 = (const float*)d_in[18];
    const float* b2 = (const float*)d_in[19];
    const float* w3 = (const float*)d_in[20];
    const float* b3 = (const float*)d_in[21];
    float* out = (float*)d_out;

    const int* esrc = ei;
    const int* edst = ei + E;

    // workspace layout (~60 MB)
    char* ws = (char*)d_ws;
    size_t off = 0;
    auto alloc = [&](size_t bytes) {
        size_t r = off;
        off = (off + bytes + 255) & ~(size_t)255;
        return r;
    };
    int* lofs = (int*)(ws + alloc((size_t)SCAT_BLOCKS * LOFS_W * 4));
    int2* re = (int2*)(ws + alloc((size_t)N * 8));
    unsigned int* soff = (unsigned int*)(ws + alloc((size_t)NB * CAP * 4));
    unsigned int* ebuf = (unsigned int*)(ws + alloc((size_t)SCAT_BLOCKS * EDGES_PER_BLOCK * 4));
    unsigned short* hbA = (unsigned short*)(ws + alloc((size_t)N * 64 * 2 + 128));
    unsigned short* hbB = (unsigned short*)(ws + alloc((size_t)N * 64 * 2 + 128));
    unsigned short* aggb = (unsigned short*)(ws + alloc((size_t)N * 64 * 2));
    unsigned short* wt = (unsigned short*)(ws + alloc((size_t)4 * 64 * 128 * 2));

    // 1. prep: mega (LDS bucket-sort scatter + f2b + wprep), then fscatter2
    k_mega<<<SCAT_BLOCKS + F2B_BLOCKS + WPREP_BLOCKS, 256, 0, stream>>>(
        esrc, edst, lofs, ebuf, (const float4*)x, (uint2*)hbA,
        wroot[0], wrel[0], wroot[1], wrel[1],
        wroot[2], wrel[2], wroot[3], wrel[3], wt);
    k_fscatter2<<<NB, 256, 0, stream>>>(ebuf, lofs, re, soff, hbA, hbB, N);

    // 2. four conv layers (bf16 h ping-pong, MFMA gemm)
    int agg_blocks = (N * 64 + 255) / 256;   // one wave per node
    int gemm_blocks = (N + 63) / 64;         // 64-node tile per block

    k_agg<<<agg_blocks, 256, 0, stream>>>(hbA, aggb, re, soff, N);
    k_gemm<1><<<gemm_blocks, 256, 0, stream>>>(hbA, aggb, wt + 0 * 8192, brel[0], hbB, N);

    k_agg<<<agg_blocks, 256, 0, stream>>>(hbB, aggb, re, soff, N);
    k_gemm<1><<<gemm_blocks, 256, 0, stream>>>(hbB, aggb, wt + 1 * 8192, brel[1], hbA, N);

    k_agg<<<agg_blocks, 256, 0, stream>>>(hbA, aggb, re, soff, N);
    k_gemm<1><<<gemm_blocks, 256, 0, stream>>>(hbA, aggb, wt + 2 * 8192, brel[2], hbB, N);

    k_agg<<<agg_blocks, 256, 0, stream>>>(hbB, aggb, re, soff, N);
    k_gemm<0><<<gemm_blocks, 256, 0, stream>>>(hbB, aggb, wt + 3 * 8192, brel[3], hbA, N);

    // 3. fused pooling + MLP head
    k_poolmlp<<<G, 256, 0, stream>>>(hbA, batch, T, w1, b1, w2, b2, w3, b3, out, N);
}